// Round 12
// baseline (175.854 us; speedup 1.0000x reference)
//
#include <hip/hip_runtime.h>

typedef unsigned short u16;
typedef __attribute__((ext_vector_type(8))) short short8;
typedef __attribute__((ext_vector_type(4))) float floatx4;

#define AS1 __attribute__((address_space(1)))
#define AS3 __attribute__((address_space(3)))

__device__ __forceinline__ u16 f2bf(float f) {
  unsigned u = __float_as_uint(f);
  u += 0x7fffu + ((u >> 16) & 1u);
  return (u16)(u >> 16);
}

// ---- prep: blocks [0,769) = weight/bias convert; [769,1793) = gn partials --
__global__ void prep(const float* __restrict__ Wq, const float* __restrict__ Wk,
                     const float* __restrict__ Wv, const float* __restrict__ bq,
                     const float* __restrict__ bk, const float* __restrict__ bv,
                     u16* __restrict__ wqkv, float* __restrict__ bqkv,
                     const float* __restrict__ x, float* __restrict__ partials) {
  int bid = blockIdx.x, t = threadIdx.x;
  if (bid < 768) {
    const float* src = bid < 256 ? Wq + bid * 256
                     : bid < 512 ? Wk + (bid - 256) * 256
                                 : Wv + (bid - 512) * 256;
    wqkv[bid * 256 + t] = f2bf(src[t]);
    return;
  }
  if (bid == 768) {
    for (int i = 0; i < 3; ++i) {
      int d = i * 256 + t;
      float v = d < 256 ? bq[d] : d < 512 ? bk[d - 256] : bv[d - 512];
      bqkv[d] = v;
    }
    return;
  }
  int pb = bid - 769;             // 0..1023
  int g = pb >> 4, part = pb & 15;
  const float4* b4 = (const float4*)(x + (size_t)g * 65536 + part * 4096);
  float s = 0.f, s2 = 0.f;
  for (int i = 0; i < 4; ++i) {
    float4 v = b4[i * 256 + t];
    s += v.x + v.y + v.z + v.w;
    s2 += v.x * v.x + v.y * v.y + v.z * v.z + v.w * v.w;
  }
  for (int off = 32; off; off >>= 1) {
    s += __shfl_xor(s, off);
    s2 += __shfl_xor(s2, off);
  }
  __shared__ float red[8];
  int wave = t >> 6, lane = t & 63;
  if (lane == 0) { red[wave] = s; red[4 + wave] = s2; }
  __syncthreads();
  if (t == 0) {
    partials[pb * 2]     = red[0] + red[1] + red[2] + red[3];
    partials[pb * 2 + 1] = red[4] + red[5] + red[6] + red[7];
  }
}

// ------- groupnorm apply + transpose: h[b][p][c] bf16 (64x64 LDS tiles) -----
__global__ void gn_apply(const float* __restrict__ x, const float* __restrict__ gamma,
                         const float* __restrict__ beta, const float* __restrict__ partials,
                         u16* __restrict__ h) {
  __shared__ float tile[64][65];
  __shared__ float s_stats[2];
  int p0 = blockIdx.x * 64, c0 = blockIdx.y * 64, b = blockIdx.z;
  int t = threadIdx.x;
  int g = b * 4 + blockIdx.y;
  if (t < 16) {
    float s  = partials[(g * 16 + t) * 2];
    float s2 = partials[(g * 16 + t) * 2 + 1];
    for (int off = 8; off; off >>= 1) {
      s += __shfl_xor(s, off, 16);
      s2 += __shfl_xor(s2, off, 16);
    }
    if (t == 0) {
      float mean = s * (1.f / 65536.f);
      float var = s2 * (1.f / 65536.f) - mean * mean;
      s_stats[0] = mean;
      s_stats[1] = rsqrtf(var + 1e-5f);
    }
  }
  __syncthreads();
  float mean = s_stats[0], rstd = s_stats[1];
  int cl = t >> 4, p4 = t & 15;
  for (int i = 0; i < 4; ++i) {
    int c = cl + i * 16;
    float gm = gamma[c0 + c] * rstd;
    float bt = beta[c0 + c] - mean * gm;
    float4 v = *(const float4*)(x + ((size_t)(b * 256 + c0 + c)) * 1024 + p0 + p4 * 4);
    tile[c][p4 * 4 + 0] = v.x * gm + bt;
    tile[c][p4 * 4 + 1] = v.y * gm + bt;
    tile[c][p4 * 4 + 2] = v.z * gm + bt;
    tile[c][p4 * 4 + 3] = v.w * gm + bt;
  }
  __syncthreads();
  int pr = t >> 3, c8 = t & 7;
  for (int i = 0; i < 2; ++i) {
    int p = pr + i * 32;
    union { u16 us[8]; uint4 v4; } tmp;
    for (int j = 0; j < 8; ++j) tmp.us[j] = f2bf(tile[c8 * 8 + j][p]);
    *(uint4*)(h + ((size_t)(b * 1024 + p0 + p)) * 256 + c0 + c8 * 8) = tmp.v4;
  }
}

// ---------------- QKV GEMM: 128x128x32 tiles, 512 threads (R11) -------------
__global__ __launch_bounds__(512) void gemm_qkv(
    const u16* __restrict__ A, const u16* __restrict__ B,
    const float* __restrict__ bias,
    u16* __restrict__ o0, u16* __restrict__ o1, u16* __restrict__ o2) {
  __shared__ u16 As[4 * 128 * 8];  // 8 KB, chunk-major [kc 4][row 128][8]
  __shared__ u16 Bs[4 * 128 * 8];  // 8 KB
  int b = blockIdx.z;
  int m0 = blockIdx.x * 128, n0 = blockIdx.y * 128;
  const u16* Ab = A + (size_t)b * 262144 + (size_t)m0 * 256;
  const u16* Bb = B + (size_t)n0 * 256;
  int t = threadIdx.x, w = t >> 6, lane = t & 63;
  int q = lane >> 4, r16 = lane & 15;
  int wm = w & 1, wn = w >> 1;     // wave tile: 64 rows x 32 cols

  floatx4 acc[4][2];
#pragma unroll
  for (int i = 0; i < 4; ++i)
#pragma unroll
    for (int j = 0; j < 2; ++j) acc[i][j] = (floatx4)0.f;

  int kc = w >> 1, row = (w & 1) * 64 + lane;
  for (int ks = 0; ks < 8; ++ks) {
    int k0 = ks * 32;
    __syncthreads();
    __builtin_amdgcn_global_load_lds(
        (const AS1 void*)(Ab + (size_t)row * 256 + k0 + kc * 8),
        (AS3 void*)(As + (size_t)(w * 64) * 8), 16, 0, 0);
    __builtin_amdgcn_global_load_lds(
        (const AS1 void*)(Bb + (size_t)row * 256 + k0 + kc * 8),
        (AS3 void*)(Bs + (size_t)(w * 64) * 8), 16, 0, 0);
    __syncthreads();
    short8 af[4], bfr[2];
#pragma unroll
    for (int mi = 0; mi < 4; ++mi)
      af[mi] = *(const short8*)(As + (size_t)(q * 128 + wm * 64 + mi * 16 + r16) * 8);
#pragma unroll
    for (int ni = 0; ni < 2; ++ni)
      bfr[ni] = *(const short8*)(Bs + (size_t)(q * 128 + wn * 32 + ni * 16 + r16) * 8);
#pragma unroll
    for (int mi = 0; mi < 4; ++mi)
#pragma unroll
      for (int ni = 0; ni < 2; ++ni)
        acc[mi][ni] = __builtin_amdgcn_mfma_f32_16x16x32_bf16(af[mi], bfr[ni], acc[mi][ni], 0, 0, 0);
  }

#pragma unroll
  for (int ni = 0; ni < 2; ++ni) {
    int dcol = n0 + wn * 32 + ni * 16 + r16;
    float bv_ = bias[dcol];
#pragma unroll
    for (int mi = 0; mi < 4; ++mi)
#pragma unroll
      for (int rg = 0; rg < 4; ++rg) {
        int mrow = m0 + wm * 64 + mi * 16 + q * 4 + rg;
        u16 hv = f2bf(acc[mi][ni][rg] + bv_);
        if (dcol < 256)
          o0[((size_t)b * 1024 + mrow) * 256 + dcol] = hv;
        else if (dcol < 512)
          o1[((size_t)b * 1024 + mrow) * 256 + (dcol - 256)] = hv;
        else
          o2[((size_t)b * 256 + (dcol - 512)) * 1024 + mrow] = hv;  // vT[d][n]
      }
  }
}

// ---------------- fused flash attention v7 ----------------------------------
// S computed TRANSPOSED: mfma(kf, qf) -> C-layout (col=r16=qrow, row=key).
// P goes register->register into the PV A-operand layout via 8 shfl + 4
// selects — Ps LDS round-trip and the mid-jt barrier are GONE. K/V double-
// buffered (128.5 KB): ONE barrier per jt; DMA(jt+1) issued right after it,
// covered by the full jt compute. Waves free-run S->exp->PV (convoy broken).
// Wave (wq,kh): S^T for 16 qrows (wq) x 32 keys (kh); PV over its 32 keys x
// all 256 d; kh-pairs merge O at the end through a 64 KB LDS scratch.
__global__ __launch_bounds__(512) void flash_attn(
    const u16* __restrict__ qb, const u16* __restrict__ kb,
    const u16* __restrict__ vT, const float* __restrict__ xres,
    float* __restrict__ outf) {
  __shared__ u16 Ks[2][16384];   // 64 KB  [buf][c-chunk 32][key 64][8]
  __shared__ u16 Vs[2][16384];   // 64 KB  [buf][j-chunk 8][d 256][8]
  __shared__ float lpart[2][64];
  int idx = blockIdx.x;
  int b = (idx & 7) | ((idx >> 7) << 3);   // XCD swizzle: batch -> one XCD
  int qt = (idx >> 3) & 15;
  int m0 = qt * 64;
  int t = threadIdx.x, w = t >> 6, lane = t & 63;
  int q = lane >> 4, r16 = lane & 15;
  int wq = w & 3;       // q-row group (16 rows)
  int kh = w >> 2;      // key-half (32 keys)
  const u16* Qb = qb + ((size_t)b * 1024 + m0) * 256;
  const u16* Kb = kb + (size_t)b * 262144;
  const u16* Vb = vT + (size_t)b * 262144;

  // stage K(0), V(0) -> buf 0
#pragma unroll
  for (int i = 0; i < 4; ++i) {
    __builtin_amdgcn_global_load_lds(
        (const AS1 void*)(Kb + (size_t)lane * 256 + (i * 8 + w) * 8),
        (AS3 void*)(Ks[0] + ((i * 8 + w) * 64) * 8), 16, 0, 0);
    int u0 = (i * 8 + w) * 64;
    int jc = u0 >> 8, d0 = u0 & 255;
    __builtin_amdgcn_global_load_lds(
        (const AS1 void*)(Vb + (size_t)(d0 + lane) * 1024 + jc * 8),
        (AS3 void*)(Vs[0] + (size_t)u0 * 8), 16, 0, 0);
  }

  // Q fragments from global (L2-resident; reused all 16 jt)
  short8 qf[8];
#pragma unroll
  for (int ks = 0; ks < 8; ++ks)
    qf[ks] = *(const short8*)(Qb + (size_t)(wq * 16 + r16) * 256 + ks * 32 + q * 8);

  float l_acc = 0.f;
  floatx4 acc_o[16];
#pragma unroll
  for (int i = 0; i < 16; ++i) acc_o[i] = (floatx4)0.f;

  const float cexp = 0.0625f * 1.44269504f;

  for (int jt = 0; jt < 16; ++jt) {
    int cur = jt & 1, nxt = cur ^ 1;
    __syncthreads();  // DMA(jt) drained; all waves done reading buf[nxt]

    if (jt < 15) {
      int j0n = (jt + 1) * 64;
#pragma unroll
      for (int i = 0; i < 4; ++i) {
        __builtin_amdgcn_global_load_lds(
            (const AS1 void*)(Kb + (size_t)(j0n + lane) * 256 + (i * 8 + w) * 8),
            (AS3 void*)(Ks[nxt] + ((i * 8 + w) * 64) * 8), 16, 0, 0);
        int u0 = (i * 8 + w) * 64;
        int jc = u0 >> 8, d0 = u0 & 255;
        __builtin_amdgcn_global_load_lds(
            (const AS1 void*)(Vb + (size_t)(d0 + lane) * 1024 + j0n + jc * 8),
            (AS3 void*)(Vs[nxt] + (size_t)u0 * 8), 16, 0, 0);
      }
    }

    // S^T = K Q^T : wave's 32 keys (2 m-tiles) x 16 qrows
    floatx4 st[2];
    st[0] = (floatx4)0.f;
    st[1] = (floatx4)0.f;
#pragma unroll
    for (int ks = 0; ks < 8; ++ks) {
#pragma unroll
      for (int tt = 0; tt < 2; ++tt) {
        short8 kf = *(const short8*)(
            Ks[cur] + (size_t)((ks * 4 + q) * 64 + kh * 32 + tt * 16 + r16) * 8);
        st[tt] = __builtin_amdgcn_mfma_f32_16x16x32_bf16(kf, qf[ks], st[tt], 0, 0, 0);
      }
    }

    // p = exp2(s*c); l accumulate (lane's qrow = wq*16+r16); pack bf16 pairs
    unsigned pk0[2], pk1[2];
#pragma unroll
    for (int h = 0; h < 2; ++h) {
      float a0 = exp2f(st[0][2 * h] * cexp), a1 = exp2f(st[0][2 * h + 1] * cexp);
      float b0 = exp2f(st[1][2 * h] * cexp), b1 = exp2f(st[1][2 * h + 1] * cexp);
      l_acc += a0 + a1 + b0 + b1;
      pk0[h] = (unsigned)f2bf(a0) | ((unsigned)f2bf(a1) << 16);
      pk1[h] = (unsigned)f2bf(b0) | ((unsigned)f2bf(b1) << 16);
    }

    // register exchange: build PV A-frag (m=qrow=r16, k=q*8+j over wave's keys)
    // dword i from lane ((q&1)*2 + (i>>1), r16), tile selected by q>>1
    int srcb = ((q & 1) * 2) * 16 + r16;
    int aex[4];
#pragma unroll
    for (int i = 0; i < 4; ++i) {
      int src = srcb + (i >> 1) * 16;
      int v0 = __shfl((int)pk0[i & 1], src);
      int v1 = __shfl((int)pk1[i & 1], src);
      aex[i] = (q >> 1) ? v1 : v0;
    }
    union { int d[4]; short8 s; } pf;
    pf.d[0] = aex[0]; pf.d[1] = aex[1]; pf.d[2] = aex[2]; pf.d[3] = aex[3];

    // O += P V : wave's 16 qrows x 256 d over its 32 keys
#pragma unroll
    for (int ni2 = 0; ni2 < 16; ++ni2) {
      short8 bf = *(const short8*)(
          Vs[cur] + (size_t)((kh * 4 + q) * 256 + ni2 * 16 + r16) * 8);
      acc_o[ni2] = __builtin_amdgcn_mfma_f32_16x16x32_bf16(pf.s, bf, acc_o[ni2], 0, 0, 0);
    }
  }

  // l: reduce over q (lanes with same r16), publish per (kh, qrow)
  l_acc += __shfl_xor(l_acc, 16);
  l_acc += __shfl_xor(l_acc, 32);
  if (q == 0) lpart[kh][wq * 16 + r16] = l_acc;
  __syncthreads();  // also: all PV reads of Ks/Vs done before scratch reuse

  // merge O across kh pairs through LDS scratch (reuse Ks area, 64 KB)
  float* mbuf = (float*)&Ks[0][0];
  if (kh == 1) {
#pragma unroll
    for (int ni2 = 0; ni2 < 16; ++ni2)
      *(float4*)&mbuf[(size_t)((wq * 16 + ni2) * 64 + lane) * 4] =
          *(float4*)&acc_o[ni2];
  }
  __syncthreads();
  if (kh == 0) {
    float inv[4];
#pragma unroll
    for (int rg = 0; rg < 4; ++rg) {
      int row = wq * 16 + q * 4 + rg;
      inv[rg] = 1.f / (lpart[0][row] + lpart[1][row]);
    }
#pragma unroll
    for (int ni2 = 0; ni2 < 16; ++ni2) {
      float4 m = *(float4*)&mbuf[(size_t)((wq * 16 + ni2) * 64 + lane) * 4];
      int d = ni2 * 16 + r16;
      size_t go = ((size_t)b * 256 + d) * 1024 + m0 + wq * 16 + q * 4;
      float4 xv = *(const float4*)(xres + go);
      float4 o;
      o.x = (acc_o[ni2][0] + m.x) * inv[0] + xv.x;
      o.y = (acc_o[ni2][1] + m.y) * inv[1] + xv.y;
      o.z = (acc_o[ni2][2] + m.z) * inv[2] + xv.z;
      o.w = (acc_o[ni2][3] + m.w) * inv[3] + xv.w;
      *(float4*)(outf + go) = o;
    }
  }
}

extern "C" void kernel_launch(void* const* d_in, const int* in_sizes, int n_in,
                              void* d_out, int out_size, void* d_ws, size_t ws_size,
                              hipStream_t stream) {
  (void)in_sizes; (void)n_in; (void)out_size; (void)ws_size;
  const float* x     = (const float*)d_in[0];
  const float* Wq    = (const float*)d_in[1];
  const float* bq    = (const float*)d_in[2];
  const float* Wk    = (const float*)d_in[3];
  const float* bk    = (const float*)d_in[4];
  const float* Wv    = (const float*)d_in[5];
  const float* bv    = (const float*)d_in[6];
  const float* gamma = (const float*)d_in[7];
  const float* beta  = (const float*)d_in[8];
  float* out = (float*)d_out;
  char* ws = (char*)d_ws;

  u16*   h      = (u16*)(ws);                                  // 8 MiB
  u16*   wqkv   = (u16*)(ws + (8u << 20));                     // 384 KiB
  float* bqkv   = (float*)(ws + (8u << 20) + (384u << 10));    // 3 KiB
  float* statsP = (float*)(ws + (8u << 20) + (400u << 10));    // 8 KiB
  u16*   qb     = (u16*)(ws + (9u << 20));                     // 8 MiB
  u16*   kb     = (u16*)(ws + (17u << 20));                    // 8 MiB
  u16*   vT     = (u16*)(ws + (25u << 20));                    // 8 MiB

  hipLaunchKernelGGL(prep, dim3(1793), dim3(256), 0, stream,
                     Wq, Wk, Wv, bq, bk, bv, wqkv, bqkv, x, statsP);
  hipLaunchKernelGGL(gn_apply, dim3(16, 4, 16), dim3(256), 0, stream,
                     x, gamma, beta, statsP, h);
  hipLaunchKernelGGL(gemm_qkv, dim3(8, 6, 16), dim3(512), 0, stream,
                     h, wqkv, bqkv, qb, kb, vT);
  hipLaunchKernelGGL(flash_attn, dim3(256), dim3(512), 0, stream, qb, kb, vT, x, out);
}